// Round 1
// baseline (297.704 us; speedup 1.0000x reference)
//
#include <hip/hip_runtime.h>

#define WDIM 1920
#define HDIM 1080
#define TPB 256

// ws layout: ws[0] = float total loss sum, ws[1] = uint valid count
__global__ __launch_bounds__(TPB) void bce_main(const float* __restrict__ px,
                                                const float* __restrict__ py,
                                                const int* __restrict__ tgt,
                                                float* __restrict__ ws) {
    const int pair = blockIdx.x;          // b*N + n
    const int t = threadIdx.x;

    int tx = tgt[pair * 2 + 0];
    int ty = tgt[pair * 2 + 1];
    tx = min(max(tx, 0), WDIM - 1);
    ty = min(max(ty, 0), HDIM - 1);
    const bool valid = !(tx == 0 && ty == 0);

    const float4* rx = (const float4*)(px + (size_t)pair * WDIM);
    const float4* ry = (const float4*)(py + (size_t)pair * HDIM);

    const float LN2 = 0.69314718056f;
    float sx = 0.f, sy = 0.f;

    // sum of clamped log1p(-p) over the x row (480 float4s)
    for (int i = t; i < WDIM / 4; i += TPB) {
        float4 v = rx[i];
        sx += fmaxf(__log2f(1.f - v.x) * LN2, -100.f);
        sx += fmaxf(__log2f(1.f - v.y) * LN2, -100.f);
        sx += fmaxf(__log2f(1.f - v.z) * LN2, -100.f);
        sx += fmaxf(__log2f(1.f - v.w) * LN2, -100.f);
    }
    // y row (270 float4s)
    for (int i = t; i < HDIM / 4; i += TPB) {
        float4 v = ry[i];
        sy += fmaxf(__log2f(1.f - v.x) * LN2, -100.f);
        sy += fmaxf(__log2f(1.f - v.y) * LN2, -100.f);
        sy += fmaxf(__log2f(1.f - v.z) * LN2, -100.f);
        sy += fmaxf(__log2f(1.f - v.w) * LN2, -100.f);
    }

    // target-element correction: loss*L = (l1p_t - lp_t) - sum_l1p
    float ex = 0.f, ey = 0.f;
    if (t == 0) {
        float pt = px[(size_t)pair * WDIM + tx];
        float qt = py[(size_t)pair * HDIM + ty];
        ex = fmaxf(__log2f(1.f - pt) * LN2, -100.f) - fmaxf(__log2f(pt) * LN2, -100.f);
        ey = fmaxf(__log2f(1.f - qt) * LN2, -100.f) - fmaxf(__log2f(qt) * LN2, -100.f);
    }

    float v = (ex - sx) * (1.0f / WDIM) + (ey - sy) * (1.0f / HDIM);

    // wave (64-lane) reduce
    #pragma unroll
    for (int o = 32; o > 0; o >>= 1) v += __shfl_down(v, o, 64);

    __shared__ float red[TPB / 64];
    if ((t & 63) == 0) red[t >> 6] = v;
    __syncthreads();

    if (t == 0) {
        float bs = 0.f;
        #pragma unroll
        for (int w = 0; w < TPB / 64; ++w) bs += red[w];
        if (valid) {
            atomicAdd(ws, bs);
            atomicAdd((unsigned int*)(ws + 1), 1u);
        }
    }
}

__global__ void bce_final(const float* __restrict__ ws, float* __restrict__ out) {
    float cnt = (float)((const unsigned int*)ws)[1];
    out[0] = ws[0] / fmaxf(cnt, 1.0f);
}

extern "C" void kernel_launch(void* const* d_in, const int* in_sizes, int n_in,
                              void* d_out, int out_size, void* d_ws, size_t ws_size,
                              hipStream_t stream) {
    const float* px = (const float*)d_in[0];
    const float* py = (const float*)d_in[1];
    const int* tgt  = (const int*)d_in[2];
    float* out = (float*)d_out;
    float* ws  = (float*)d_ws;

    const int pairs = in_sizes[0] / WDIM;   // B*N = 8192

    hipMemsetAsync(d_ws, 0, 8, stream);
    bce_main<<<dim3(pairs), dim3(TPB), 0, stream>>>(px, py, tgt, ws);
    bce_final<<<1, 1, 0, stream>>>(ws, out);
}

// Round 2
// 115.978 us; speedup vs baseline: 2.5669x; 2.5669x over previous
//
#include <hip/hip_runtime.h>

#define WDIM 1920
#define HDIM 1080
#define TPB 256
#define PPB 4   // pairs per block; 8192/4 = 2048 blocks = 8 blocks/CU

__device__ __forceinline__ float clog1m(float p) {
    // max(log(1-p), -100)
    return fmaxf(__log2f(1.f - p) * 0.69314718056f, -100.f);
}
__device__ __forceinline__ float clog(float p) {
    return fmaxf(__log2f(p) * 0.69314718056f, -100.f);
}

__global__ __launch_bounds__(TPB) void bce_main(const float* __restrict__ px,
                                                const float* __restrict__ py,
                                                const int* __restrict__ tgt,
                                                float* __restrict__ partial_loss,
                                                float* __restrict__ partial_cnt) {
    const int t = threadIdx.x;
    float acc = 0.f;
    float cnt = 0.f;
    const int p0 = blockIdx.x * PPB;

    for (int k = 0; k < PPB; ++k) {
        const int pair = p0 + k;
        int tx = tgt[pair * 2 + 0];
        int ty = tgt[pair * 2 + 1];
        tx = min(max(tx, 0), WDIM - 1);
        ty = min(max(ty, 0), HDIM - 1);
        const float vm = (tx == 0 && ty == 0) ? 0.f : 1.f;

        const float4* rx = (const float4*)(px + (size_t)pair * WDIM);
        const float4* ry = (const float4*)(py + (size_t)pair * HDIM);
        const float4 z4 = make_float4(0.f, 0.f, 0.f, 0.f);

        // issue all loads up front for ILP; padded slots are zero -> log term 0
        float4 a0 = rx[t];                                      // covers 0..255 of 480
        float4 a1 = (t < WDIM / 4 - TPB) ? rx[t + TPB] : z4;    // covers 256..479 (t<224)
        float4 b0 = ry[t];                                      // covers 0..255 of 270
        float4 b1 = (t < HDIM / 4 - TPB) ? ry[t + TPB] : z4;    // covers 256..269 (t<14)

        float sx = clog1m(a0.x) + clog1m(a0.y) + clog1m(a0.z) + clog1m(a0.w)
                 + clog1m(a1.x) + clog1m(a1.y) + clog1m(a1.z) + clog1m(a1.w);
        float sy = clog1m(b0.x) + clog1m(b0.y) + clog1m(b0.z) + clog1m(b0.w)
                 + clog1m(b1.x) + clog1m(b1.y) + clog1m(b1.z) + clog1m(b1.w);

        // target-element correction, one lane per pair
        float corr = 0.f;
        if (t == 0) {
            float pt = px[(size_t)pair * WDIM + tx];
            float qt = py[(size_t)pair * HDIM + ty];
            corr = (clog1m(pt) - clog(pt)) * (1.f / WDIM)
                 + (clog1m(qt) - clog(qt)) * (1.f / HDIM);
            cnt += vm;
        }
        acc += vm * (corr - sx * (1.f / WDIM) - sy * (1.f / HDIM));
    }

    // block reduce (no atomics anywhere)
    #pragma unroll
    for (int o = 32; o > 0; o >>= 1) acc += __shfl_down(acc, o, 64);
    __shared__ float red[TPB / 64];
    if ((t & 63) == 0) red[t >> 6] = acc;
    __syncthreads();
    if (t == 0) {
        float bs = red[0] + red[1] + red[2] + red[3];
        partial_loss[blockIdx.x] = bs;
        partial_cnt[blockIdx.x]  = cnt;
    }
}

__global__ __launch_bounds__(TPB) void bce_final(const float* __restrict__ pl,
                                                 const float* __restrict__ pc,
                                                 int nblk, float* __restrict__ out) {
    const int t = threadIdx.x;
    float s = 0.f, c = 0.f;
    for (int i = t; i < nblk; i += TPB) { s += pl[i]; c += pc[i]; }
    #pragma unroll
    for (int o = 32; o > 0; o >>= 1) {
        s += __shfl_down(s, o, 64);
        c += __shfl_down(c, o, 64);
    }
    __shared__ float rs[TPB / 64], rc[TPB / 64];
    if ((t & 63) == 0) { rs[t >> 6] = s; rc[t >> 6] = c; }
    __syncthreads();
    if (t == 0) {
        float ts = rs[0] + rs[1] + rs[2] + rs[3];
        float tc = rc[0] + rc[1] + rc[2] + rc[3];
        out[0] = ts / fmaxf(tc, 1.f);
    }
}

extern "C" void kernel_launch(void* const* d_in, const int* in_sizes, int n_in,
                              void* d_out, int out_size, void* d_ws, size_t ws_size,
                              hipStream_t stream) {
    const float* px = (const float*)d_in[0];
    const float* py = (const float*)d_in[1];
    const int* tgt  = (const int*)d_in[2];
    float* out = (float*)d_out;

    const int pairs = in_sizes[0] / WDIM;   // B*N = 8192
    const int nblk  = pairs / PPB;          // 2048

    float* pl = (float*)d_ws;
    float* pc = pl + nblk;

    bce_main<<<dim3(nblk), dim3(TPB), 0, stream>>>(px, py, tgt, pl, pc);
    bce_final<<<1, TPB, 0, stream>>>(pl, pc, nblk, out);
}